// Round 1
// baseline (432.984 us; speedup 1.0000x reference)
//
#include <hip/hip_runtime.h>

// MHA fused forward for B=4,T=2048,E=1024,H=16,D=64 on gfx950.
// Pipeline: prep (bf16 cast + weight transpose) -> GEMM1 (QKV) -> flash attn -> GEMM2 (out proj).

typedef __attribute__((ext_vector_type(8))) __bf16 bf16x8;
typedef __attribute__((ext_vector_type(4))) float f32x4;
typedef __attribute__((ext_vector_type(4))) unsigned int u32x4;
typedef __attribute__((ext_vector_type(2))) unsigned int u32x2;
typedef unsigned short u16;
typedef unsigned int u32;

#define DEV __device__ __forceinline__

DEV u16 f2bf(float f) {          // round-to-nearest-even f32 -> bf16 (inputs never NaN)
  u32 u = __builtin_bit_cast(u32, f);
  u += 0x7fffu + ((u >> 16) & 1u);
  return (u16)(u >> 16);
}
DEV u32 pack2(float a, float b) { return (u32)f2bf(a) | ((u32)f2bf(b) << 16); }

// ---------------------------------------------------------------- prep: x->bf16, bias concat
__global__ __launch_bounds__(256) void prep_x_kernel(
    const float* __restrict__ x, const float* __restrict__ bq, const float* __restrict__ bk,
    const float* __restrict__ bv, u16* __restrict__ xbf, float* __restrict__ bqkv) {
  int gid = blockIdx.x * 256 + threadIdx.x;   // grid covers 8,388,608/8 = 1,048,576 threads
  if (gid < 3072) {
    float v = (gid < 1024) ? bq[gid] : (gid < 2048 ? bk[gid - 1024] : bv[gid - 2048]);
    bqkv[gid] = v;
  }
  const float4* xv = (const float4*)x;
  float4 f0 = xv[(size_t)gid * 2];
  float4 f1 = xv[(size_t)gid * 2 + 1];
  u32x4 st;
  st.x = pack2(f0.x, f0.y); st.y = pack2(f0.z, f0.w);
  st.z = pack2(f1.x, f1.y); st.w = pack2(f1.z, f1.w);
  *(u32x4*)&xbf[(size_t)gid * 8] = st;
}

// ---------------------------------------------------------------- prep: weight transposes to B^T bf16
// Wq/Wk/Wv [H][E][D] -> wqkvT[c = p*1024 + h*64 + d][e] ; Wp [E][E] -> wpT[f][e]
__global__ __launch_bounds__(256) void prep_w_kernel(
    const float* __restrict__ Wq, const float* __restrict__ Wk, const float* __restrict__ Wv,
    const float* __restrict__ Wp, u16* __restrict__ wqkvT, u16* __restrict__ wpT) {
  __shared__ float t[64][65];
  int bid = blockIdx.x, tid = threadIdx.x;
  int r0 = tid >> 6, c = tid & 63;
  if (bid < 768) {
    int p = bid >> 8, rem = bid & 255, h = rem >> 4, et = rem & 15;
    const float* src = (p == 0 ? Wq : (p == 1 ? Wk : Wv)) + ((size_t)h * 1024 + et * 64) * 64;
#pragma unroll
    for (int i = 0; i < 16; i++) { int e = r0 + i * 4; t[e][c] = src[(size_t)e * 64 + c]; }
    __syncthreads();
    u16* dst = wqkvT + ((size_t)p * 1024 + h * 64) * 1024 + et * 64;
#pragma unroll
    for (int i = 0; i < 16; i++) { int d = r0 + i * 4; dst[(size_t)d * 1024 + c] = f2bf(t[c][d]); }
  } else {
    int b2 = bid - 768, rt = b2 >> 4, ct = b2 & 15;
#pragma unroll
    for (int i = 0; i < 16; i++) { int e = r0 + i * 4; t[e][c] = Wp[(size_t)(rt * 64 + e) * 1024 + ct * 64 + c]; }
    __syncthreads();
#pragma unroll
    for (int i = 0; i < 16; i++) { int f = r0 + i * 4; wpT[(size_t)(ct * 64 + f) * 1024 + rt * 64 + c] = f2bf(t[c][f]); }
  }
}

// ---------------------------------------------------------------- GEMM 128x128 tile, K=1024, BK=64
// A [M][1024] bf16 row-major, Bt [N][1024] bf16 row-major (B^T). XOR swizzle slot^=(row&7),
// applied on the *global source* (global_load_lds writes linearly) and on the ds_read address.
DEV void stage_tile(const u16* __restrict__ X, int row0, int k0, u16* lds, int tid) {
#pragma unroll
  for (int j = 0; j < 4; j++) {
    int ci = j * 256 + tid;                 // 1024 chunks of 16B = 128 rows x 8 slots
    int row = ci >> 3, slot = ci & 7;
    int srcslot = slot ^ (row & 7);
    const u16* gp = X + (size_t)(row0 + row) * 1024 + k0 + srcslot * 8;
    __builtin_amdgcn_global_load_lds((const __attribute__((address_space(1))) void*)gp,
                                     (__attribute__((address_space(3))) void*)(lds + ci * 8),
                                     16, 0, 0);
  }
}

__global__ __launch_bounds__(256) void gemm128_kernel(
    const u16* __restrict__ A, const u16* __restrict__ Bt, const float* __restrict__ bias,
    int tilesN, int mode, u16* __restrict__ Qb, u16* __restrict__ Kb, u16* __restrict__ VTb,
    float* __restrict__ outF) {
  __shared__ u16 As[128 * 64];
  __shared__ u16 Bs[128 * 64];
  int nwg = gridDim.x;
  int bid = blockIdx.x;
  int swz = (bid % 8) * (nwg / 8) + bid / 8;    // XCD-contiguous (nwg % 8 == 0)
  int bm = swz / tilesN, bn = swz % tilesN;
  int tid = threadIdx.x;
  int lane = tid & 63, wave = tid >> 6;
  int wm = wave >> 1, wn = wave & 1;
  int lr = lane & 15, lg = lane >> 4;

  f32x4 acc[4][4];
#pragma unroll
  for (int i = 0; i < 4; i++)
#pragma unroll
    for (int j = 0; j < 4; j++) acc[i][j] = f32x4{0.f, 0.f, 0.f, 0.f};

  for (int k0 = 0; k0 < 1024; k0 += 64) {
    stage_tile(A, bm * 128, k0, As, tid);
    stage_tile(Bt, bn * 128, k0, Bs, tid);
    __syncthreads();
#pragma unroll
    for (int kf = 0; kf < 2; kf++) {
      bf16x8 af[4], bfr[4];
#pragma unroll
      for (int i = 0; i < 4; i++) {
        int ra = wm * 64 + i * 16 + lr;
        af[i] = *(const bf16x8*)&As[ra * 64 + (((lg + kf * 4) ^ (ra & 7)) * 8)];
        int rb = wn * 64 + i * 16 + lr;
        bfr[i] = *(const bf16x8*)&Bs[rb * 64 + (((lg + kf * 4) ^ (rb & 7)) * 8)];
      }
#pragma unroll
      for (int i = 0; i < 4; i++)
#pragma unroll
        for (int j = 0; j < 4; j++)
          acc[i][j] = __builtin_amdgcn_mfma_f32_16x16x32_bf16(af[i], bfr[j], acc[i][j], 0, 0, 0);
    }
    __syncthreads();
  }

  int crow = bm * 128 + wm * 64;
  int ccol = bn * 128 + wn * 64;
  if (mode == 0) {   // QKV epilogue: +bias, ->bf16, scatter to Q/K [bh][t][d], V -> VT [bh][d][t]
#pragma unroll
    for (int j = 0; j < 4; j++) {
      int col = ccol + j * 16 + lr;
      float bb = bias[col];
      int p = col >> 10, h = (col >> 6) & 15, d = col & 63;
#pragma unroll
      for (int i = 0; i < 4; i++) {
        int row0 = crow + i * 16 + lg * 4;
        int b_ = row0 >> 11, t0 = row0 & 2047;
        if (p == 2) {
          u32x2 pv;
          pv.x = pack2(acc[i][j][0] + bb, acc[i][j][1] + bb);
          pv.y = pack2(acc[i][j][2] + bb, acc[i][j][3] + bb);
          *(u32x2*)&VTb[((size_t)(b_ * 16 + h) * 64 + d) * 2048 + t0] = pv;
        } else {
          u16* dst = (p == 0 ? Qb : Kb);
#pragma unroll
          for (int r = 0; r < 4; r++)
            dst[((size_t)(b_ * 16 + h) * 2048 + (t0 + r)) * 64 + d] = f2bf(acc[i][j][r] + bb);
        }
      }
    }
  } else {           // final projection epilogue: +bias, fp32 out
#pragma unroll
    for (int j = 0; j < 4; j++) {
      int col = ccol + j * 16 + lr;
      float bb = bias[col];
#pragma unroll
      for (int i = 0; i < 4; i++) {
        int row0 = crow + i * 16 + lg * 4;
#pragma unroll
        for (int r = 0; r < 4; r++)
          outF[(size_t)(row0 + r) * 1024 + col] = acc[i][j][r] + bb;
      }
    }
  }
}

// ---------------------------------------------------------------- flash attention (causal)
// One block = one (b,h) x 64 q-rows; 4 independent waves x 16 q-rows.
// Swapped form: S^T = mfma(A=K_frag, B=Q^T_frag); O^T = mfma(A=V^T_frag, B=P^T_frag).
__global__ __launch_bounds__(256) void attn_kernel(
    const u16* __restrict__ Qb, const u16* __restrict__ Kb, const u16* __restrict__ VTb,
    u16* __restrict__ cat) {
  int bid = blockIdx.x;                      // 2048
  int swz = (bid & 7) * 256 + (bid >> 3);    // group one head's q-tiles on one XCD
  int bh = swz >> 5, qt = swz & 31;
  int b = bh >> 4, h = bh & 15;
  int tid = threadIdx.x, wave = tid >> 6, lane = tid & 63;
  int lr = lane & 15, lg = lane >> 4;
  int q0 = qt * 64 + wave * 16;
  int q_lane = q0 + lr;

  const u16* Qh = Qb + (size_t)bh * 2048 * 64;
  const u16* Kh = Kb + (size_t)bh * 2048 * 64;
  const u16* Vh = VTb + (size_t)bh * 64 * 2048;

  bf16x8 qf0 = *(const bf16x8*)&Qh[(size_t)(q0 + lr) * 64 + lg * 8];
  bf16x8 qf1 = *(const bf16x8*)&Qh[(size_t)(q0 + lr) * 64 + 32 + lg * 8];

  f32x4 o[4];
#pragma unroll
  for (int df = 0; df < 4; df++) o[df] = f32x4{0.f, 0.f, 0.f, 0.f};
  float m_run = -1e30f, l_run = 0.f;

  for (int kv0 = 0; kv0 <= q0 + 15; kv0 += 64) {
    f32x4 s[4];
#pragma unroll
    for (int nf = 0; nf < 4; nf++) {
      f32x4 a = f32x4{0.f, 0.f, 0.f, 0.f};
      const u16* kr = &Kh[(size_t)(kv0 + nf * 16 + lr) * 64 + lg * 8];
      a = __builtin_amdgcn_mfma_f32_16x16x32_bf16(*(const bf16x8*)kr, qf0, a, 0, 0, 0);
      a = __builtin_amdgcn_mfma_f32_16x16x32_bf16(*(const bf16x8*)(kr + 32), qf1, a, 0, 0, 0);
      s[nf] = a;
    }
    bool needmask = (kv0 + 63 > q0);
    float tmax = -1e30f;
#pragma unroll
    for (int nf = 0; nf < 4; nf++)
#pragma unroll
      for (int r = 0; r < 4; r++) {
        float v = s[nf][r] * 0.125f;
        if (needmask) { int kv = kv0 + nf * 16 + lg * 4 + r; if (kv > q_lane) v = -1e30f; }
        s[nf][r] = v;
        tmax = fmaxf(tmax, v);
      }
    tmax = fmaxf(tmax, __shfl_xor(tmax, 16));
    tmax = fmaxf(tmax, __shfl_xor(tmax, 32));
    float m_new = fmaxf(m_run, tmax);
    float corr = __expf(m_run - m_new);
    float tsum = 0.f;
#pragma unroll
    for (int nf = 0; nf < 4; nf++)
#pragma unroll
      for (int r = 0; r < 4; r++) { float p = __expf(s[nf][r] - m_new); s[nf][r] = p; tsum += p; }
    tsum += __shfl_xor(tsum, 16);
    tsum += __shfl_xor(tsum, 32);
    l_run = l_run * corr + tsum;
    m_run = m_new;
#pragma unroll
    for (int df = 0; df < 4; df++) o[df] = o[df] * corr;

    // P^T (C-layout) -> B-operand frags via lane redistribution
    u32 a01[4], a23[4];
#pragma unroll
    for (int nf = 0; nf < 4; nf++) {
      a01[nf] = pack2(s[nf][0], s[nf][1]);
      a23[nf] = pack2(s[nf][2], s[nf][3]);
    }
    int g1 = lg >> 1;
    int s0l = (lg & 1) * 32 + lr, s1l = s0l + 16;
#pragma unroll
    for (int kf = 0; kf < 2; kf++) {
      u32 xA, xB, w0, w1, w2, w3;
      xA = __shfl(a01[kf * 2], s0l); xB = __shfl(a01[kf * 2 + 1], s0l); w0 = g1 ? xB : xA;
      xA = __shfl(a23[kf * 2], s0l); xB = __shfl(a23[kf * 2 + 1], s0l); w1 = g1 ? xB : xA;
      xA = __shfl(a01[kf * 2], s1l); xB = __shfl(a01[kf * 2 + 1], s1l); w2 = g1 ? xB : xA;
      xA = __shfl(a23[kf * 2], s1l); xB = __shfl(a23[kf * 2 + 1], s1l); w3 = g1 ? xB : xA;
      u32x4 wv; wv.x = w0; wv.y = w1; wv.z = w2; wv.w = w3;
      bf16x8 pfrag = __builtin_bit_cast(bf16x8, wv);
#pragma unroll
      for (int df = 0; df < 4; df++) {
        const u16* vr = &Vh[(size_t)(df * 16 + lr) * 2048 + kv0 + kf * 32 + lg * 8];
        o[df] = __builtin_amdgcn_mfma_f32_16x16x32_bf16(*(const bf16x8*)vr, pfrag, o[df], 0, 0, 0);
      }
    }
  }

  float linv = 1.0f / l_run;
#pragma unroll
  for (int df = 0; df < 4; df++) {
    u32x2 st;
    st.x = pack2(o[df][0] * linv, o[df][1] * linv);
    st.y = pack2(o[df][2] * linv, o[df][3] * linv);
    *(u32x2*)&cat[(size_t)(b * 2048 + q0 + lr) * 1024 + h * 64 + df * 16 + lg * 4] = st;
  }
}

// ---------------------------------------------------------------- launch
extern "C" void kernel_launch(void* const* d_in, const int* in_sizes, int n_in,
                              void* d_out, int out_size, void* d_ws, size_t ws_size,
                              hipStream_t stream) {
  const float* x  = (const float*)d_in[0];
  const float* Wq = (const float*)d_in[1];
  const float* bq = (const float*)d_in[2];
  const float* Wk = (const float*)d_in[3];
  const float* bk = (const float*)d_in[4];
  const float* Wv = (const float*)d_in[5];
  const float* bv = (const float*)d_in[6];
  const float* Wp = (const float*)d_in[7];
  const float* bp = (const float*)d_in[8];

  char* w = (char*)d_ws;
  u16* xbf    = (u16*)w;                 w += (size_t)8192 * 1024 * 2;   // 16 MiB
  u16* wqkvT  = (u16*)w;                 w += (size_t)3072 * 1024 * 2;   // 6 MiB
  u16* wpT    = (u16*)w;                 w += (size_t)1024 * 1024 * 2;   // 2 MiB
  float* bqkv = (float*)w;               w += (size_t)3072 * 4;
  u16* Qb     = (u16*)w;                 w += (size_t)64 * 2048 * 64 * 2;
  u16* Kb     = (u16*)w;                 w += (size_t)64 * 2048 * 64 * 2;
  u16* VTb    = (u16*)w;                 w += (size_t)64 * 64 * 2048 * 2;
  u16* cat    = (u16*)w;                 w += (size_t)8192 * 1024 * 2;

  prep_x_kernel<<<4096, 256, 0, stream>>>(x, bq, bk, bv, xbf, bqkv);
  prep_w_kernel<<<1024, 256, 0, stream>>>(Wq, Wk, Wv, Wp, wqkvT, wpT);
  gemm128_kernel<<<1536, 256, 0, stream>>>(xbf, wqkvT, bqkv, 24, 0, Qb, Kb, VTb, nullptr);
  attn_kernel<<<2048, 256, 0, stream>>>(Qb, Kb, VTb, cat);
  gemm128_kernel<<<512, 256, 0, stream>>>(cat, wpT, bp, 8, 1, nullptr, nullptr, nullptr, (float*)d_out);
}

// Round 2
// 225.472 us; speedup vs baseline: 1.9203x; 1.9203x over previous
//
#include <hip/hip_runtime.h>

// MHA fused forward for B=4,T=2048,E=1024,H=16,D=64 on gfx950.
// Pipeline: prep (bf16 cast + weight transpose) -> GEMM1 (QKV) -> flash attn -> GEMM2 (out proj).

typedef __attribute__((ext_vector_type(8))) __bf16 bf16x8;
typedef __attribute__((ext_vector_type(4))) float f32x4;
typedef __attribute__((ext_vector_type(4))) unsigned int u32x4;
typedef __attribute__((ext_vector_type(2))) unsigned int u32x2;
typedef unsigned short u16;
typedef unsigned int u32;

#define DEV __device__ __forceinline__

DEV u16 f2bf(float f) {          // round-to-nearest-even f32 -> bf16 (inputs never NaN)
  u32 u = __builtin_bit_cast(u32, f);
  u += 0x7fffu + ((u >> 16) & 1u);
  return (u16)(u >> 16);
}
DEV u32 pack2(float a, float b) { return (u32)f2bf(a) | ((u32)f2bf(b) << 16); }

// ---------------------------------------------------------------- prep: x->bf16, bias concat
__global__ __launch_bounds__(256) void prep_x_kernel(
    const float* __restrict__ x, const float* __restrict__ bq, const float* __restrict__ bk,
    const float* __restrict__ bv, u16* __restrict__ xbf, float* __restrict__ bqkv) {
  int gid = blockIdx.x * 256 + threadIdx.x;
  if (gid < 3072) {
    float v = (gid < 1024) ? bq[gid] : (gid < 2048 ? bk[gid - 1024] : bv[gid - 2048]);
    bqkv[gid] = v;
  }
  const float4* xv = (const float4*)x;
  float4 f0 = xv[(size_t)gid * 2];
  float4 f1 = xv[(size_t)gid * 2 + 1];
  u32x4 st;
  st.x = pack2(f0.x, f0.y); st.y = pack2(f0.z, f0.w);
  st.z = pack2(f1.x, f1.y); st.w = pack2(f1.z, f1.w);
  *(u32x4*)&xbf[(size_t)gid * 8] = st;
}

// ---------------------------------------------------------------- prep: weight transposes to B^T bf16
__global__ __launch_bounds__(256) void prep_w_kernel(
    const float* __restrict__ Wq, const float* __restrict__ Wk, const float* __restrict__ Wv,
    const float* __restrict__ Wp, u16* __restrict__ wqkvT, u16* __restrict__ wpT) {
  __shared__ float t[64][65];
  int bid = blockIdx.x, tid = threadIdx.x;
  int r0 = tid >> 6, c = tid & 63;
  if (bid < 768) {
    int p = bid >> 8, rem = bid & 255, h = rem >> 4, et = rem & 15;
    const float* src = (p == 0 ? Wq : (p == 1 ? Wk : Wv)) + ((size_t)h * 1024 + et * 64) * 64;
#pragma unroll
    for (int i = 0; i < 16; i++) { int e = r0 + i * 4; t[e][c] = src[(size_t)e * 64 + c]; }
    __syncthreads();
    u16* dst = wqkvT + ((size_t)p * 1024 + h * 64) * 1024 + et * 64;
#pragma unroll
    for (int i = 0; i < 16; i++) { int d = r0 + i * 4; dst[(size_t)d * 1024 + c] = f2bf(t[c][d]); }
  } else {
    int b2 = bid - 768, rt = b2 >> 4, ct = b2 & 15;
#pragma unroll
    for (int i = 0; i < 16; i++) { int e = r0 + i * 4; t[e][c] = Wp[(size_t)(rt * 64 + e) * 1024 + ct * 64 + c]; }
    __syncthreads();
#pragma unroll
    for (int i = 0; i < 16; i++) { int f = r0 + i * 4; wpT[(size_t)(ct * 64 + f) * 1024 + rt * 64 + c] = f2bf(t[c][f]); }
  }
}

// ---------------------------------------------------------------- GEMM 128x128 tile, K=1024, BK=64
DEV void stage_tile(const u16* __restrict__ X, int row0, int k0, u16* lds, int tid) {
#pragma unroll
  for (int j = 0; j < 4; j++) {
    int ci = j * 256 + tid;
    int row = ci >> 3, slot = ci & 7;
    int srcslot = slot ^ (row & 7);
    const u16* gp = X + (size_t)(row0 + row) * 1024 + k0 + srcslot * 8;
    __builtin_amdgcn_global_load_lds((const __attribute__((address_space(1))) void*)gp,
                                     (__attribute__((address_space(3))) void*)(lds + ci * 8),
                                     16, 0, 0);
  }
}

__global__ __launch_bounds__(256) void gemm128_kernel(
    const u16* __restrict__ A, const u16* __restrict__ Bt, const float* __restrict__ bias,
    int tilesN, int mode, u16* __restrict__ Qb, u16* __restrict__ Kb, u16* __restrict__ VTb,
    float* __restrict__ outF) {
  __shared__ u16 As[128 * 64];
  __shared__ u16 Bs[128 * 64];
  int nwg = gridDim.x;
  int bid = blockIdx.x;
  int swz = (bid % 8) * (nwg / 8) + bid / 8;
  int bm = swz / tilesN, bn = swz % tilesN;
  int tid = threadIdx.x;
  int lane = tid & 63, wave = tid >> 6;
  int wm = wave >> 1, wn = wave & 1;
  int lr = lane & 15, lg = lane >> 4;

  f32x4 acc[4][4];
#pragma unroll
  for (int i = 0; i < 4; i++)
#pragma unroll
    for (int j = 0; j < 4; j++) acc[i][j] = f32x4{0.f, 0.f, 0.f, 0.f};

  for (int k0 = 0; k0 < 1024; k0 += 64) {
    stage_tile(A, bm * 128, k0, As, tid);
    stage_tile(Bt, bn * 128, k0, Bs, tid);
    __syncthreads();
#pragma unroll
    for (int kf = 0; kf < 2; kf++) {
      bf16x8 af[4], bfr[4];
#pragma unroll
      for (int i = 0; i < 4; i++) {
        int ra = wm * 64 + i * 16 + lr;
        af[i] = *(const bf16x8*)&As[ra * 64 + (((lg + kf * 4) ^ (ra & 7)) * 8)];
        int rb = wn * 64 + i * 16 + lr;
        bfr[i] = *(const bf16x8*)&Bs[rb * 64 + (((lg + kf * 4) ^ (rb & 7)) * 8)];
      }
      __builtin_amdgcn_s_setprio(1);
#pragma unroll
      for (int i = 0; i < 4; i++)
#pragma unroll
        for (int j = 0; j < 4; j++)
          acc[i][j] = __builtin_amdgcn_mfma_f32_16x16x32_bf16(af[i], bfr[j], acc[i][j], 0, 0, 0);
      __builtin_amdgcn_s_setprio(0);
    }
    __syncthreads();
  }

  int crow = bm * 128 + wm * 64;
  int ccol = bn * 128 + wn * 64;
  if (mode == 0) {
#pragma unroll
    for (int j = 0; j < 4; j++) {
      int col = ccol + j * 16 + lr;
      float bb = bias[col];
      int p = col >> 10, h = (col >> 6) & 15, d = col & 63;
#pragma unroll
      for (int i = 0; i < 4; i++) {
        int row0 = crow + i * 16 + lg * 4;
        int b_ = row0 >> 11, t0 = row0 & 2047;
        if (p == 2) {
          u32x2 pv;
          pv.x = pack2(acc[i][j][0] + bb, acc[i][j][1] + bb);
          pv.y = pack2(acc[i][j][2] + bb, acc[i][j][3] + bb);
          *(u32x2*)&VTb[((size_t)(b_ * 16 + h) * 64 + d) * 2048 + t0] = pv;
        } else {
          u16* dst = (p == 0 ? Qb : Kb);
#pragma unroll
          for (int r = 0; r < 4; r++)
            dst[((size_t)(b_ * 16 + h) * 2048 + (t0 + r)) * 64 + d] = f2bf(acc[i][j][r] + bb);
        }
      }
    }
  } else {
#pragma unroll
    for (int j = 0; j < 4; j++) {
      int col = ccol + j * 16 + lr;
      float bb = bias[col];
#pragma unroll
      for (int i = 0; i < 4; i++) {
        int row0 = crow + i * 16 + lg * 4;
#pragma unroll
        for (int r = 0; r < 4; r++)
          outF[(size_t)(row0 + r) * 1024 + col] = acc[i][j][r] + bb;
      }
    }
  }
}

// ---------------------------------------------------------------- flash attention (causal)
// Paired causal tiles: block handles q-tiles (p, 31-p) of one (b,h) -> uniform work (33 tile
// computes/block). K/V staged once per block in double-buffered LDS (global_load_lds, XOR
// swizzle both sides), shared by 4 waves and both contexts.
struct BTrue  { static constexpr bool value = true;  };
struct BFalse { static constexpr bool value = false; };

DEV void stage_kv(const u16* __restrict__ Kh, const u16* __restrict__ Vh, int kv0,
                  u16* Ksb, u16* Vsb, int tid) {
#pragma unroll
  for (int j = 0; j < 2; j++) {
    int ci = j * 256 + tid;                 // 512 chunks of 16B = 64 rows x 8 slots
    int row = ci >> 3, slot = ci & 7;
    int ss = slot ^ (row & 7);
    __builtin_amdgcn_global_load_lds(
        (const __attribute__((address_space(1))) void*)(Kh + (size_t)(kv0 + row) * 64 + ss * 8),
        (__attribute__((address_space(3))) void*)(Ksb + ci * 8), 16, 0, 0);
    __builtin_amdgcn_global_load_lds(
        (const __attribute__((address_space(1))) void*)(Vh + (size_t)row * 2048 + kv0 + ss * 8),
        (__attribute__((address_space(3))) void*)(Vsb + ci * 8), 16, 0, 0);
  }
}

DEV void softmax_ctx(f32x4 s[4], float& m_run, float& l_run, f32x4 o[4],
                     bool needmask, int kv0, int q_lane, int lg,
                     u32 a01[4], u32 a23[4]) {
  float tmax = -1e30f;
#pragma unroll
  for (int nf = 0; nf < 4; nf++)
#pragma unroll
    for (int r = 0; r < 4; r++) {
      float v = s[nf][r] * 0.125f;
      if (needmask) { int kv = kv0 + nf * 16 + lg * 4 + r; if (kv > q_lane) v = -1e30f; }
      s[nf][r] = v;
      tmax = fmaxf(tmax, v);
    }
  tmax = fmaxf(tmax, __shfl_xor(tmax, 16));
  tmax = fmaxf(tmax, __shfl_xor(tmax, 32));
  float m_new = fmaxf(m_run, tmax);
  float corr = __expf(m_run - m_new);
  float tsum = 0.f;
#pragma unroll
  for (int nf = 0; nf < 4; nf++)
#pragma unroll
    for (int r = 0; r < 4; r++) { float p = __expf(s[nf][r] - m_new); s[nf][r] = p; tsum += p; }
  tsum += __shfl_xor(tsum, 16);
  tsum += __shfl_xor(tsum, 32);
  l_run = l_run * corr + tsum;
  m_run = m_new;
#pragma unroll
  for (int df = 0; df < 4; df++) o[df] = o[df] * corr;
#pragma unroll
  for (int nf = 0; nf < 4; nf++) {
    a01[nf] = pack2(s[nf][0], s[nf][1]);
    a23[nf] = pack2(s[nf][2], s[nf][3]);
  }
}

DEV bf16x8 build_pfrag(const u32 a01[4], const u32 a23[4], int kf, int s0l, int s1l, int g1) {
  u32 xA, xB, w0, w1, w2, w3;
  xA = __shfl(a01[kf * 2], s0l); xB = __shfl(a01[kf * 2 + 1], s0l); w0 = g1 ? xB : xA;
  xA = __shfl(a23[kf * 2], s0l); xB = __shfl(a23[kf * 2 + 1], s0l); w1 = g1 ? xB : xA;
  xA = __shfl(a01[kf * 2], s1l); xB = __shfl(a01[kf * 2 + 1], s1l); w2 = g1 ? xB : xA;
  xA = __shfl(a23[kf * 2], s1l); xB = __shfl(a23[kf * 2 + 1], s1l); w3 = g1 ? xB : xA;
  u32x4 wv; wv.x = w0; wv.y = w1; wv.z = w2; wv.w = w3;
  return __builtin_bit_cast(bf16x8, wv);
}

__global__ __launch_bounds__(256) void attn_kernel(
    const u16* __restrict__ Qb, const u16* __restrict__ Kb, const u16* __restrict__ VTb,
    u16* __restrict__ cat) {
  __shared__ u16 Ks[2][64 * 64];
  __shared__ u16 Vs[2][64 * 64];
  int bid = blockIdx.x;                       // 1024 = 64 bh x 16 pairs
  int swz = (bid & 7) * 128 + (bid >> 3);     // heads grouped per XCD
  int bh = swz >> 4, p = swz & 15;
  int qa = p, qb = 31 - p;
  int b = bh >> 4, h = bh & 15;
  int tid = threadIdx.x, wave = tid >> 6, lane = tid & 63;
  int lr = lane & 15, lg = lane >> 4;
  int g1 = lg >> 1;
  int s0l = (lg & 1) * 32 + lr, s1l = s0l + 16;

  const u16* Qh = Qb + (size_t)bh * 2048 * 64;
  const u16* Kh = Kb + (size_t)bh * 2048 * 64;
  const u16* Vh = VTb + (size_t)bh * 64 * 2048;

  int q0a = qa * 64 + wave * 16;
  int q0b = qb * 64 + wave * 16;

  bf16x8 qaf0 = *(const bf16x8*)&Qh[(size_t)(q0a + lr) * 64 + lg * 8];
  bf16x8 qaf1 = *(const bf16x8*)&Qh[(size_t)(q0a + lr) * 64 + 32 + lg * 8];
  bf16x8 qbf0 = *(const bf16x8*)&Qh[(size_t)(q0b + lr) * 64 + lg * 8];
  bf16x8 qbf1 = *(const bf16x8*)&Qh[(size_t)(q0b + lr) * 64 + 32 + lg * 8];

  f32x4 oA[4], oB[4];
#pragma unroll
  for (int df = 0; df < 4; df++) { oA[df] = f32x4{0.f, 0.f, 0.f, 0.f}; oB[df] = f32x4{0.f, 0.f, 0.f, 0.f}; }
  float mA = -1e30f, lA = 0.f, mB = -1e30f, lB = 0.f;

  stage_kv(Kh, Vh, 0, Ks[0], Vs[0], tid);
  __syncthreads();
  int cur = 0;

  for (int kvt = 0; kvt <= qb; ++kvt) {
    int kv0 = kvt * 64;
    if (kvt < qb) stage_kv(Kh, Vh, kv0 + 64, Ks[cur ^ 1], Vs[cur ^ 1], tid);

    auto tile_body = [&](auto actc) {
      constexpr bool ACT = decltype(actc)::value;
      f32x4 sB[4], sA[4];
#pragma unroll
      for (int nf = 0; nf < 4; nf++) { sB[nf] = f32x4{0.f, 0.f, 0.f, 0.f}; if (ACT) sA[nf] = f32x4{0.f, 0.f, 0.f, 0.f}; }
#pragma unroll
      for (int half = 0; half < 2; half++) {
        bf16x8 qB = half ? qbf1 : qbf0;
        bf16x8 qA = half ? qaf1 : qaf0;
        __builtin_amdgcn_s_setprio(1);
#pragma unroll
        for (int nf = 0; nf < 4; nf++) {
          int row = nf * 16 + lr;
          bf16x8 kfr = *(const bf16x8*)&Ks[cur][row * 64 + (((lg + half * 4) ^ (row & 7)) * 8)];
          sB[nf] = __builtin_amdgcn_mfma_f32_16x16x32_bf16(kfr, qB, sB[nf], 0, 0, 0);
          if (ACT) sA[nf] = __builtin_amdgcn_mfma_f32_16x16x32_bf16(kfr, qA, sA[nf], 0, 0, 0);
        }
        __builtin_amdgcn_s_setprio(0);
      }
      u32 b01[4], b23[4], c01[4], c23[4];
      softmax_ctx(sB, mB, lB, oB, kvt == qb, kv0, q0b + lr, lg, b01, b23);
      if (ACT) softmax_ctx(sA, mA, lA, oA, kvt == qa, kv0, q0a + lr, lg, c01, c23);
#pragma unroll
      for (int kf = 0; kf < 2; kf++) {
        bf16x8 pB = build_pfrag(b01, b23, kf, s0l, s1l, g1);
        bf16x8 pA;
        if (ACT) pA = build_pfrag(c01, c23, kf, s0l, s1l, g1);
        __builtin_amdgcn_s_setprio(1);
#pragma unroll
        for (int df = 0; df < 4; df++) {
          int row = df * 16 + lr;
          bf16x8 vf = *(const bf16x8*)&Vs[cur][row * 64 + (((kf * 4 + lg) ^ (row & 7)) * 8)];
          oB[df] = __builtin_amdgcn_mfma_f32_16x16x32_bf16(vf, pB, oB[df], 0, 0, 0);
          if (ACT) oA[df] = __builtin_amdgcn_mfma_f32_16x16x32_bf16(vf, pA, oA[df], 0, 0, 0);
        }
        __builtin_amdgcn_s_setprio(0);
      }
    };
    if (kvt <= qa) tile_body(BTrue{}); else tile_body(BFalse{});

    __syncthreads();
    cur ^= 1;
  }

  float linvA = 1.0f / lA, linvB = 1.0f / lB;
#pragma unroll
  for (int df = 0; df < 4; df++) {
    u32x2 stA, stB;
    stA.x = pack2(oA[df][0] * linvA, oA[df][1] * linvA);
    stA.y = pack2(oA[df][2] * linvA, oA[df][3] * linvA);
    *(u32x2*)&cat[(size_t)(b * 2048 + q0a + lr) * 1024 + h * 64 + df * 16 + lg * 4] = stA;
    stB.x = pack2(oB[df][0] * linvB, oB[df][1] * linvB);
    stB.y = pack2(oB[df][2] * linvB, oB[df][3] * linvB);
    *(u32x2*)&cat[(size_t)(b * 2048 + q0b + lr) * 1024 + h * 64 + df * 16 + lg * 4] = stB;
  }
}

// ---------------------------------------------------------------- launch
extern "C" void kernel_launch(void* const* d_in, const int* in_sizes, int n_in,
                              void* d_out, int out_size, void* d_ws, size_t ws_size,
                              hipStream_t stream) {
  const float* x  = (const float*)d_in[0];
  const float* Wq = (const float*)d_in[1];
  const float* bq = (const float*)d_in[2];
  const float* Wk = (const float*)d_in[3];
  const float* bk = (const float*)d_in[4];
  const float* Wv = (const float*)d_in[5];
  const float* bv = (const float*)d_in[6];
  const float* Wp = (const float*)d_in[7];
  const float* bp = (const float*)d_in[8];

  char* w = (char*)d_ws;
  u16* xbf    = (u16*)w;                 w += (size_t)8192 * 1024 * 2;
  u16* wqkvT  = (u16*)w;                 w += (size_t)3072 * 1024 * 2;
  u16* wpT    = (u16*)w;                 w += (size_t)1024 * 1024 * 2;
  float* bqkv = (float*)w;               w += (size_t)3072 * 4;
  u16* Qb     = (u16*)w;                 w += (size_t)64 * 2048 * 64 * 2;
  u16* Kb     = (u16*)w;                 w += (size_t)64 * 2048 * 64 * 2;
  u16* VTb    = (u16*)w;                 w += (size_t)64 * 64 * 2048 * 2;
  u16* cat    = (u16*)w;                 w += (size_t)8192 * 1024 * 2;

  prep_x_kernel<<<4096, 256, 0, stream>>>(x, bq, bk, bv, xbf, bqkv);
  prep_w_kernel<<<1024, 256, 0, stream>>>(Wq, Wk, Wv, Wp, wqkvT, wpT);
  gemm128_kernel<<<1536, 256, 0, stream>>>(xbf, wqkvT, bqkv, 24, 0, Qb, Kb, VTb, nullptr);
  attn_kernel<<<1024, 256, 0, stream>>>(Qb, Kb, VTb, cat);
  gemm128_kernel<<<512, 256, 0, stream>>>(cat, wpT, bp, 8, 1, nullptr, nullptr, nullptr, (float*)d_out);
}